// Round 23
// baseline (190.467 us; speedup 1.0000x reference)
//
#include <hip/hip_runtime.h>
#include <math.h>

#define NN 2048

using f32x4 = __attribute__((ext_vector_type(4))) float;
using u32x4 = __attribute__((ext_vector_type(4))) unsigned int;
using u32x2 = __attribute__((ext_vector_type(2))) unsigned int;

__device__ __forceinline__ unsigned short f2bf(float x){
    unsigned int u = __float_as_uint(x);
    return (unsigned short)((u + 0x7FFFu + ((u>>16)&1u)) >> 16);
}
__device__ __forceinline__ float bf2f(unsigned short u){
    return __uint_as_float(((unsigned int)u) << 16);
}

// v_mfma_f32_16x16x32_bf16: D(4xf32)=A(8xbf16)*B(8xbf16)+C
__device__ __forceinline__ void mfma16(f32x4& acc, const u32x4& a, const u32x4& b) {
    asm("v_mfma_f32_16x16x32_bf16 %0, %1, %2, %0" : "+v"(acc) : "v"(a), "v"(b));
}

// ---------------- 3x3 symmetric eigen (min/max) in double ----------------
__device__ inline void eig3_minmax(double a11, double a12, double a13,
                                   double a22, double a23, double a33,
                                   double& lmin, double& lmax) {
    double p1 = a12*a12 + a13*a13 + a23*a23;
    double q  = (a11 + a22 + a33) / 3.0;
    double d1 = a11 - q, d2 = a22 - q, d3 = a33 - q;
    double p2 = d1*d1 + d2*d2 + d3*d3 + 2.0*p1;
    if (p2 <= 1e-300) { lmin = q; lmax = q; return; }
    double pp  = sqrt(p2 / 6.0);
    double inv = 1.0 / pp;
    double b11 = d1*inv, b22 = d2*inv, b33 = d3*inv;
    double b12 = a12*inv, b13 = a13*inv, b23 = a23*inv;
    double detB = b11*(b22*b33 - b23*b23) - b12*(b12*b33 - b23*b13) + b13*(b12*b23 - b22*b13);
    double r = detB * 0.5;
    r = fmin(1.0, fmax(-1.0, r));
    double phi = acos(r) / 3.0;
    lmax = q + 2.0*pp*cos(phi);
    lmin = q + 2.0*pp*cos(phi + 2.0943951023931953);
}

// ---------------- fused prep: pack_pos | conv_feat | conv_w --------------
// blocks 0..127: pack_pos ; 128..4223: conv_feat ; 4224..4351: conv_w
__global__ __launch_bounds__(256) void prep_kernel(
    const float* __restrict__ k3, float4* __restrict__ pk,
    const float* __restrict__ feat, unsigned short* __restrict__ featb,
    const float* __restrict__ w_q, const float* __restrict__ w_k,
    const float* __restrict__ w_v, const float* __restrict__ w_o,
    unsigned short* __restrict__ wb)
{
    const int B = blockIdx.x;
    if (B < 128) {
        const int i = B * 256 + threadIdx.x;
        const float x = k3[i*3+0], y = k3[i*3+1], z = k3[i*3+2];
        pk[i] = make_float4(x, y, z, x*x + y*y + z*z);
    } else if (B < 4224) {
        const size_t i = (size_t)((B - 128) * 256 + threadIdx.x) * 8;
        const float4 a = *(const float4*)(feat + i);
        const float4 b = *(const float4*)(feat + i + 4);
        u32x4 v;
        v.x = (unsigned)f2bf(a.x) | ((unsigned)f2bf(a.y) << 16);
        v.y = (unsigned)f2bf(a.z) | ((unsigned)f2bf(a.w) << 16);
        v.z = (unsigned)f2bf(b.x) | ((unsigned)f2bf(b.y) << 16);
        v.w = (unsigned)f2bf(b.z) | ((unsigned)f2bf(b.w) << 16);
        *(u32x4*)(featb + i) = v;
    } else {
        const int i = (B - 4224) * 256 + threadIdx.x;   // 0..32767
        const int sel = i >> 13;
        const size_t off = (size_t)(i & 8191) * 8;
        const float* src = (sel == 0) ? w_q : (sel == 1) ? w_k : (sel == 2) ? w_v : w_o;
        const float4 a = *(const float4*)(src + off);
        const float4 b = *(const float4*)(src + off + 4);
        u32x4 v;
        v.x = (unsigned)f2bf(a.x) | ((unsigned)f2bf(a.y) << 16);
        v.y = (unsigned)f2bf(a.z) | ((unsigned)f2bf(a.w) << 16);
        v.z = (unsigned)f2bf(b.x) | ((unsigned)f2bf(b.y) << 16);
        v.w = (unsigned)f2bf(b.z) | ((unsigned)f2bf(b.w) << 16);
        *(u32x4*)(wb + (size_t)sel * 65536 + off) = v;
    }
}

// ---------------- fused: QKV MFMA GEMM (blocks 0..1535) | kNN (1536..9727)
// Independent work items; VALU-bound knn waves overlap MFMA GEMM waves.
// All arithmetic identical to R22's separate kernels -> bit-identical out.
__global__ __launch_bounds__(256) void fused_knn_qkv(
    const float4* __restrict__ pk4, int* __restrict__ idxOut,
    const unsigned short* __restrict__ Ab, const unsigned short* __restrict__ Wball,
    const float* __restrict__ b_q, const float* __restrict__ b_k, const float* __restrict__ b_v,
    float* __restrict__ Qb, unsigned short* __restrict__ Kb, unsigned short* __restrict__ Vb)
{
    __shared__ unsigned short As[128 * 72];
    __shared__ unsigned short Bs[128 * 72];
    __shared__ unsigned long long hitbuf[4][16];
    __shared__ int hitcnt[4];

    const int B = blockIdx.x;
    const int tid = threadIdx.x;

    if (B < 1536) {
        // ---------------- QKV MFMA GEMM ----------------
        const int idx = B;
        const int by = idx % 6;
        const int m0 = (idx / 6) * 128;
        const int wsel = by >> 1;
        const int crel0 = (by & 1) * 128;
        const unsigned short* Wb = Wball + (size_t)wsel * 65536;
        const float* bv = (wsel == 0) ? b_q : ((wsel == 1) ? b_k : b_v);

        const int sr = tid >> 1, sh = (tid & 1) * 32;
        const int wid = tid >> 6, lane = tid & 63;
        const int wr = (wid >> 1) * 64, wc = (wid & 1) * 64;
        const int l15 = lane & 15, lk = (lane >> 4) * 8, lq = (lane >> 4) * 4;

        f32x4 acc[4][4];
        #pragma unroll
        for (int i = 0; i < 4; ++i)
            #pragma unroll
            for (int j = 0; j < 4; ++j) { f32x4 z = {0.f,0.f,0.f,0.f}; acc[i][j] = z; }

        for (int k0 = 0; k0 < 256; k0 += 64) {
            const unsigned short* ga = Ab + (size_t)(m0 + sr) * 256 + k0 + sh;
            u32x4 a0 = *(const u32x4*)(ga);
            u32x4 a1 = *(const u32x4*)(ga + 8);
            u32x4 a2 = *(const u32x4*)(ga + 16);
            u32x4 a3 = *(const u32x4*)(ga + 24);
            const unsigned short* gw = Wb + (size_t)(crel0 + sr) * 256 + k0 + sh;
            u32x4 b0 = *(const u32x4*)(gw);
            u32x4 b1 = *(const u32x4*)(gw + 8);
            u32x4 b2 = *(const u32x4*)(gw + 16);
            u32x4 b3 = *(const u32x4*)(gw + 24);
            __syncthreads();
            *(u32x4*)&As[sr*72 + sh     ] = a0;
            *(u32x4*)&As[sr*72 + sh +  8] = a1;
            *(u32x4*)&As[sr*72 + sh + 16] = a2;
            *(u32x4*)&As[sr*72 + sh + 24] = a3;
            *(u32x4*)&Bs[sr*72 + sh     ] = b0;
            *(u32x4*)&Bs[sr*72 + sh +  8] = b1;
            *(u32x4*)&Bs[sr*72 + sh + 16] = b2;
            *(u32x4*)&Bs[sr*72 + sh + 24] = b3;
            __syncthreads();
            #pragma unroll
            for (int ks = 0; ks < 64; ks += 32) {
                u32x4 af[4], bfr[4];
                #pragma unroll
                for (int i = 0; i < 4; ++i)  af[i]  = *(const u32x4*)&As[(wr + i*16 + l15)*72 + ks + lk];
                #pragma unroll
                for (int j = 0; j < 4; ++j)  bfr[j] = *(const u32x4*)&Bs[(wc + j*16 + l15)*72 + ks + lk];
                #pragma unroll
                for (int i = 0; i < 4; ++i)
                    #pragma unroll
                    for (int j = 0; j < 4; ++j) mfma16(acc[i][j], af[i], bfr[j]);
            }
        }
        #pragma unroll
        for (int j = 0; j < 4; ++j) {
            const int col = crel0 + wc + j*16 + l15;
            const float biasv = bv[col];
            #pragma unroll
            for (int i = 0; i < 4; ++i)
                #pragma unroll
                for (int r = 0; r < 4; ++r) {
                    const int m = m0 + wr + i*16 + lq + r;
                    const float v = acc[i][j][r] + biasv;
                    if (wsel == 0)      Qb[(size_t)m * 256 + col] = v;
                    else if (wsel == 1) Kb[(size_t)m * 256 + col] = f2bf(v);
                    else                Vb[(size_t)m * 256 + col] = f2bf(v);
                }
        }
    } else {
        // ---------------- kNN scan (R19-proven) ----------------
        const int blk = B - 1536;
        const int wave = tid >> 6, lane = tid & 63;
        const int p = blk * 4 + wave;
        const int b = p >> 11, n = p & (NN - 1);
        const float4* pb = pk4 + (size_t)b * NN;
        const float4 me = pb[n];
        const float xn2 = -2.f*me.x, yn2 = -2.f*me.y, zn2 = -2.f*me.z, cn = me.w;

        if (lane == 0) hitcnt[wave] = 0;

        float dk[8];
        #pragma unroll
        for (int t = 0; t < 8; ++t) dk[t] = 1e30f;
        float d2s[32];

        #define INS(c4, jj, s) { \
            float d2 = cn + c4.w; \
            d2 = fmaf(xn2, c4.x, d2); \
            d2 = fmaf(yn2, c4.y, d2); \
            d2 = fmaf(zn2, c4.z, d2); \
            if ((jj) == n) d2 = 1e30f; \
            d2s[s] = d2; \
            dk[7] = __builtin_amdgcn_fmed3f(dk[6], dk[7], d2); \
            dk[6] = __builtin_amdgcn_fmed3f(dk[5], dk[6], d2); \
            dk[5] = __builtin_amdgcn_fmed3f(dk[4], dk[5], d2); \
            dk[4] = __builtin_amdgcn_fmed3f(dk[3], dk[4], d2); \
            dk[3] = __builtin_amdgcn_fmed3f(dk[2], dk[3], d2); \
            dk[2] = __builtin_amdgcn_fmed3f(dk[1], dk[2], d2); \
            dk[1] = __builtin_amdgcn_fmed3f(dk[0], dk[1], d2); \
            dk[0] = fminf(dk[0], d2); }

        #pragma unroll
        for (int i = 0; i < 8; ++i) {
            const int j0 = lane + i * 256;
            const float4 q0 = pb[j0];
            const float4 q1 = pb[j0 + 64];
            const float4 q2 = pb[j0 + 128];
            const float4 q3 = pb[j0 + 192];
            INS(q0, j0,       i*4 + 0)
            INS(q1, j0 + 64,  i*4 + 1)
            INS(q2, j0 + 128, i*4 + 2)
            INS(q3, j0 + 192, i*4 + 3)
        }
        #undef INS

        #define CSWAPV(a,c) { float lo = fminf(dk[a], dk[c]); float hi = fmaxf(dk[a], dk[c]); dk[a] = lo; dk[c] = hi; }
        #pragma unroll
        for (int m = 1; m < 64; m <<= 1) {
            float od[8];
            #pragma unroll
            for (int t = 0; t < 8; ++t) od[t] = __shfl_xor(dk[7 - t], m);
            #pragma unroll
            for (int t = 0; t < 8; ++t) dk[t] = fminf(dk[t], od[t]);
            CSWAPV(0,4) CSWAPV(1,5) CSWAPV(2,6) CSWAPV(3,7)
            CSWAPV(0,2) CSWAPV(1,3) CSWAPV(4,6) CSWAPV(5,7)
            CSWAPV(0,1) CSWAPV(2,3) CSWAPV(4,5) CSWAPV(6,7)
        }
        #undef CSWAPV

        const float tau = dk[7];

        #pragma unroll
        for (int s = 0; s < 32; ++s) {
            if (d2s[s] <= tau) {
                const int j = lane + (s >> 2) * 256 + (s & 3) * 64;
                unsigned u = __float_as_uint(d2s[s]);
                u ^= (u >> 31) ? 0xFFFFFFFFu : 0x80000000u;
                const int slot = atomicAdd(&hitcnt[wave], 1);
                if (slot < 16)
                    hitbuf[wave][slot] = ((unsigned long long)u << 32) | (unsigned)j;
            }
        }

        if (lane == 0) {
            int cnt = hitcnt[wave]; if (cnt > 16) cnt = 16;
            int outv[8];
            if (cnt == 8) {
                #pragma unroll
                for (int t = 0; t < 8; ++t)
                    outv[t] = (int)(unsigned)hitbuf[wave][t];
            } else {
                unsigned used = 0;
                #pragma unroll
                for (int t = 0; t < 8; ++t) {
                    unsigned long long best = ~0ull; int bi = 0;
                    #pragma unroll
                    for (int i = 0; i < 16; ++i) {
                        unsigned long long v = (i < cnt && !((used >> i) & 1u))
                                             ? hitbuf[wave][i] : ~0ull;
                        if (v < best) { best = v; bi = i; }
                    }
                    used |= 1u << bi;
                    outv[t] = (int)(unsigned)best;
                }
            }
            u32x4 v0; v0.x = outv[0]; v0.y = outv[1]; v0.z = outv[2]; v0.w = outv[3];
            u32x4 v1; v1.x = outv[4]; v1.y = outv[5]; v1.z = outv[6]; v1.w = outv[7];
            *(u32x4*)(idxOut + (size_t)p * 8)     = v0;
            *(u32x4*)(idxOut + (size_t)p * 8 + 4) = v1;
        }
    }
}

// ---------------- geometry: one LANE per point; bias f32 + h f32 ---------
__global__ __launch_bounds__(256) void geom_kernel(
    const float4* __restrict__ pk4, const int* __restrict__ knnIdx,
    const float* __restrict__ gw1, const float* __restrict__ gb1,
    const float* __restrict__ w_a, const float* __restrict__ b_a,
    float* __restrict__ biasOut, float* __restrict__ h32) {
    const int p = blockIdx.x * 256 + threadIdx.x;
    const int b = p >> 11, n = p & (NN - 1);
    const float4* pb = pk4 + (size_t)b * NN;
    const float4 me = pb[n];
    const float xn2 = -2.f*me.x, yn2 = -2.f*me.y, zn2 = -2.f*me.z, cn = me.w;

    int ik[8];
    *(u32x4*)&ik[0] = *(const u32x4*)(knnIdx + (size_t)p * 8);
    *(u32x4*)&ik[4] = *(const u32x4*)(knnIdx + (size_t)p * 8 + 4);

    float dist[8], px[8], py[8], pz[8];
    #pragma unroll
    for (int t = 0; t < 8; ++t) {
        const float4 q = pb[ik[t]];
        float d2 = cn + q.w;
        d2 = fmaf(xn2, q.x, d2);
        d2 = fmaf(yn2, q.y, d2);
        d2 = fmaf(zn2, q.z, d2);
        dist[t] = sqrtf(fmaxf(d2, 0.0f));
        px[t] = q.x; py[t] = q.y; pz[t] = q.z;
    }
    float mean = 0.f;
    #pragma unroll
    for (int t = 0; t < 8; ++t) mean += dist[t];
    mean *= 0.125f;
    float var = 0.f;
    #pragma unroll
    for (int t = 0; t < 8; ++t) { float d = dist[t] - mean; var += d * d; }
    const float stdd = sqrtf(var / 7.0f);

    float cx = 0.f, cy = 0.f, cz = 0.f;
    #pragma unroll
    for (int t = 0; t < 8; ++t) { cx += px[t]; cy += py[t]; cz += pz[t]; }
    cx *= 0.125f; cy *= 0.125f; cz *= 0.125f;
    const float relx = me.x - cx, rely = me.y - cy, relz = me.z - cz;

    double a11=0, a12=0, a13=0, a22=0, a23=0, a33=0;
    #pragma unroll
    for (int t = 0; t < 8; ++t) {
        double ux = (double)(px[t] - cx), uy = (double)(py[t] - cy), uz = (double)(pz[t] - cz);
        a11 += ux*ux; a12 += ux*uy; a13 += ux*uz;
        a22 += uy*uy; a23 += uy*uz; a33 += uz*uz;
    }
    a11 *= 0.125; a12 *= 0.125; a13 *= 0.125; a22 *= 0.125; a23 *= 0.125; a33 *= 0.125;
    double lmin, lmax;
    eig3_minmax(a11, a12, a13, a22, a23, a33, lmin, lmax);
    const float aniso = (float)(lmax / (lmin + 1e-8));

    float wa[28], ba[4];
    #pragma unroll
    for (int i = 0; i < 28; ++i) wa[i] = w_a[i];
    #pragma unroll
    for (int h = 0; h < 4; ++h) ba[h] = b_a[h];
    #pragma unroll
    for (int t = 0; t < 8; ++t) {
        f32x4 v;
        #pragma unroll
        for (int h = 0; h < 4; ++h) {
            v[h] = wa[h*7+0]*dist[t] + wa[h*7+1]*mean + wa[h*7+2]*stdd
                 + wa[h*7+3]*relx + wa[h*7+4]*rely + wa[h*7+5]*relz
                 + wa[h*7+6]*aniso + ba[h];
        }
        *(f32x4*)(biasOut + ((size_t)p*8 + t) * 4) = v;
    }

    const float g0 = mean, g1 = mean, g2 = stdd, g3 = relx, g4 = rely, g5 = relz, g6 = aniso;
    float* hrow = h32 + (size_t)p * 64;
    #pragma unroll
    for (int cq = 0; cq < 16; ++cq) {
        f32x4 hv;
        #pragma unroll
        for (int r = 0; r < 4; ++r) {
            const int c = cq*4 + r;
            float h = gw1[c*7+0]*g0 + gw1[c*7+1]*g1 + gw1[c*7+2]*g2 + gw1[c*7+3]*g3
                    + gw1[c*7+4]*g4 + gw1[c*7+5]*g5 + gw1[c*7+6]*g6 + gb1[c];
            hv[r] = fmaxf(h, 0.0f);
        }
        *(f32x4*)(hrow + cq*4) = hv;
    }
}

// ---------------- fused: enc f32 GEMM (blocks 0..511) | attn (512..8703) -
__global__ __launch_bounds__(256) void fused_enc_attn(
    const float* __restrict__ h32, const float* __restrict__ gw2,
    const float* __restrict__ gb2, float* __restrict__ encOut,
    const float* __restrict__ Qb, const unsigned short* __restrict__ Kb,
    const unsigned short* __restrict__ Vb, const int* __restrict__ knnIdx,
    const float* __restrict__ biasb, unsigned short* __restrict__ aggb)
{
    __shared__ float As[16][132];
    __shared__ float Bs[16][132];
    const int Bx = blockIdx.x;
    const int tid = threadIdx.x;

    if (Bx < 512) {
        // ---------------- enc: out = h32(32768x64) @ gw2^T + gb2 ----------
        constexpr int K = 64;
        const int m0 = (Bx >> 1) * 128;
        const int c0 = (Bx & 1) * 128;
        const int tx = tid & 15;
        const int ty = tid >> 4;
        const int lr = tid & 127;
        const int kh = (tid >> 7) * 8;

        float acc[8][8] = {};

        const float* ga = h32 + (size_t)(m0 + lr) * K + kh;
        const float* gb = gw2 + (size_t)(c0 + lr) * K + kh;

        float4 av0 = *(const float4*)(ga);
        float4 av1 = *(const float4*)(ga + 4);
        float4 bv0 = *(const float4*)(gb);
        float4 bv1 = *(const float4*)(gb + 4);

        for (int k0 = 0; k0 < K; k0 += 16) {
            __syncthreads();
            As[kh+0][lr]=av0.x; As[kh+1][lr]=av0.y; As[kh+2][lr]=av0.z; As[kh+3][lr]=av0.w;
            As[kh+4][lr]=av1.x; As[kh+5][lr]=av1.y; As[kh+6][lr]=av1.z; As[kh+7][lr]=av1.w;
            Bs[kh+0][lr]=bv0.x; Bs[kh+1][lr]=bv0.y; Bs[kh+2][lr]=bv0.z; Bs[kh+3][lr]=bv0.w;
            Bs[kh+4][lr]=bv1.x; Bs[kh+5][lr]=bv1.y; Bs[kh+6][lr]=bv1.z; Bs[kh+7][lr]=bv1.w;
            if (k0 + 16 < K) {
                av0 = *(const float4*)(ga + k0 + 16);
                av1 = *(const float4*)(ga + k0 + 20);
                bv0 = *(const float4*)(gb + k0 + 16);
                bv1 = *(const float4*)(gb + k0 + 20);
            }
            __syncthreads();
            #pragma unroll
            for (int kk = 0; kk < 16; ++kk) {
                const float4 a0 = *(const float4*)&As[kk][ty*8];
                const float4 a1 = *(const float4*)&As[kk][ty*8+4];
                const float4 b0 = *(const float4*)&Bs[kk][tx*8];
                const float4 b1 = *(const float4*)&Bs[kk][tx*8+4];
                const float a[8] = {a0.x,a0.y,a0.z,a0.w,a1.x,a1.y,a1.z,a1.w};
                const float b[8] = {b0.x,b0.y,b0.z,b0.w,b1.x,b1.y,b1.z,b1.w};
                #pragma unroll
                for (int i = 0; i < 8; ++i)
                    #pragma unroll
                    for (int j = 0; j < 8; ++j)
                        acc[i][j] = fmaf(a[i], b[j], acc[i][j]);
            }
        }
        #pragma unroll
        for (int i = 0; i < 8; ++i) {
            const size_t m = m0 + ty*8 + i;
            const int c = c0 + tx*8;
            float4 v0, v1;
            v0.x = acc[i][0] + gb2[c+0];
            v0.y = acc[i][1] + gb2[c+1];
            v0.z = acc[i][2] + gb2[c+2];
            v0.w = acc[i][3] + gb2[c+3];
            v1.x = acc[i][4] + gb2[c+4];
            v1.y = acc[i][5] + gb2[c+5];
            v1.z = acc[i][6] + gb2[c+6];
            v1.w = acc[i][7] + gb2[c+7];
            *(float4*)(encOut + m*256 + c)     = v0;
            *(float4*)(encOut + m*256 + c + 4) = v1;
        }
    } else {
        // ---------------- attn: batch->XCD swizzled gather ----------------
        const int wave = tid >> 6;
        const int lane = tid & 63;
        const int B = Bx - 512;                     // 512 % 8 == 0: swizzle preserved
        const int xcd = B & 7;
        const int k = B >> 3;
        const int batch = xcd + ((k >= 512) ? 8 : 0);
        const int p = batch * NN + ((k & 511) << 2) + wave;
        const int b = batch;
        const int h = lane >> 4;

        const float4 q = *(const float4*)(Qb + (size_t)p*256 + lane*4);

        int g[8];
        #pragma unroll
        for (int t = 0; t < 8; ++t) g[t] = b * NN + knnIdx[(size_t)p*8 + t];

        float s[8];
        #pragma unroll
        for (int t = 0; t < 8; ++t) {
            const ushort4 kv = *(const ushort4*)(Kb + (size_t)g[t]*256 + lane*4);
            float acc = q.x * bf2f(kv.x);
            acc = fmaf(q.y, bf2f(kv.y), acc);
            acc = fmaf(q.z, bf2f(kv.z), acc);
            acc = fmaf(q.w, bf2f(kv.w), acc);
            acc += __shfl_xor(acc, 1);
            acc += __shfl_xor(acc, 2);
            acc += __shfl_xor(acc, 4);
            acc += __shfl_xor(acc, 8);
            s[t] = acc * 0.125f + biasb[((size_t)p*8 + t)*4 + h];
        }

        float mx = s[0];
        #pragma unroll
        for (int t = 1; t < 8; ++t) mx = fmaxf(mx, s[t]);
        float sum = 0.f;
        #pragma unroll
        for (int t = 0; t < 8; ++t) { s[t] = expf(s[t] - mx); sum += s[t]; }
        const float inv = 1.0f / sum;

        f32x4 a = {0.f, 0.f, 0.f, 0.f};
        #pragma unroll
        for (int t = 0; t < 8; ++t) {
            const float wgt = s[t] * inv;
            const ushort4 vv = *(const ushort4*)(Vb + (size_t)g[t]*256 + lane*4);
            a[0] = fmaf(wgt, bf2f(vv.x), a[0]);
            a[1] = fmaf(wgt, bf2f(vv.y), a[1]);
            a[2] = fmaf(wgt, bf2f(vv.z), a[2]);
            a[3] = fmaf(wgt, bf2f(vv.w), a[3]);
        }
        u32x2 pk;
        pk.x = (unsigned)f2bf(a[0]) | ((unsigned)f2bf(a[1]) << 16);
        pk.y = (unsigned)f2bf(a[2]) | ((unsigned)f2bf(a[3]) << 16);
        *(u32x2*)(aggb + (size_t)p*256 + lane*4) = pk;
    }
}

// ---------------- MFMA O GEMM: bf16 weights; no-restrict aliased epilogue -
__global__ __launch_bounds__(256) void gemm_o_mfma(
    const unsigned short* __restrict__ Ab, const unsigned short* __restrict__ Wb,
    const float* __restrict__ bvec, const float* addin, float* C)
{
    __shared__ unsigned short As[128 * 72];
    __shared__ unsigned short Bs[128 * 72];
    const int tid = threadIdx.x;
    const int m0 = blockIdx.x * 128;
    const int crel0 = blockIdx.y * 128;

    const int sr = tid >> 1, sh = (tid & 1) * 32;
    const int wid = tid >> 6, lane = tid & 63;
    const int wr = (wid >> 1) * 64, wc = (wid & 1) * 64;
    const int l15 = lane & 15, lk = (lane >> 4) * 8, lq = (lane >> 4) * 4;

    f32x4 acc[4][4];
    #pragma unroll
    for (int i = 0; i < 4; ++i)
        #pragma unroll
        for (int j = 0; j < 4; ++j) { f32x4 z = {0.f,0.f,0.f,0.f}; acc[i][j] = z; }

    for (int k0 = 0; k0 < 256; k0 += 64) {
        const unsigned short* ga = Ab + (size_t)(m0 + sr) * 256 + k0 + sh;
        u32x4 a0 = *(const u32x4*)(ga);
        u32x4 a1 = *(const u32x4*)(ga + 8);
        u32x4 a2 = *(const u32x4*)(ga + 16);
        u32x4 a3 = *(const u32x4*)(ga + 24);
        const unsigned short* gw = Wb + (size_t)(crel0 + sr) * 256 + k0 + sh;
        u32x4 b0 = *(const u32x4*)(gw);
        u32x4 b1 = *(const u32x4*)(gw + 8);
        u32x4 b2 = *(const u32x4*)(gw + 16);
        u32x4 b3 = *(const u32x4*)(gw + 24);
        __syncthreads();
        *(u32x4*)&As[sr*72 + sh     ] = a0;
        *(u32x4*)&As[sr*72 + sh +  8] = a1;
        *(u32x4*)&As[sr*72 + sh + 16] = a2;
        *(u32x4*)&As[sr*72 + sh + 24] = a3;
        *(u32x4*)&Bs[sr*72 + sh     ] = b0;
        *(u32x4*)&Bs[sr*72 + sh +  8] = b1;
        *(u32x4*)&Bs[sr*72 + sh + 16] = b2;
        *(u32x4*)&Bs[sr*72 + sh + 24] = b3;
        __syncthreads();
        #pragma unroll
        for (int ks = 0; ks < 64; ks += 32) {
            u32x4 af[4], bfr[4];
            #pragma unroll
            for (int i = 0; i < 4; ++i)  af[i]  = *(const u32x4*)&As[(wr + i*16 + l15)*72 + ks + lk];
            #pragma unroll
            for (int j = 0; j < 4; ++j)  bfr[j] = *(const u32x4*)&Bs[(wc + j*16 + l15)*72 + ks + lk];
            #pragma unroll
            for (int i = 0; i < 4; ++i)
                #pragma unroll
                for (int j = 0; j < 4; ++j) mfma16(acc[i][j], af[i], bfr[j]);
        }
    }
    #pragma unroll
    for (int j = 0; j < 4; ++j) {
        const int col = crel0 + wc + j*16 + l15;
        const float biasv = bvec[col];
        #pragma unroll
        for (int i = 0; i < 4; ++i)
            #pragma unroll
            for (int r = 0; r < 4; ++r) {
                const int m = m0 + wr + i*16 + lq + r;
                const float ad = addin[(size_t)m * 256 + col];
                C[(size_t)m * 256 + col] = acc[i][j][r] + biasv + ad;
            }
    }
}

extern "C" void kernel_launch(void* const* d_in, const int* in_sizes, int n_in,
                              void* d_out, int out_size, void* d_ws, size_t ws_size,
                              hipStream_t stream) {
    const float* feat = (const float*)d_in[0];
    const float* k3   = (const float*)d_in[1];
    const float* gw1  = (const float*)d_in[2];
    const float* gb1  = (const float*)d_in[3];
    const float* gw2  = (const float*)d_in[4];
    const float* gb2  = (const float*)d_in[5];
    const float* w_q  = (const float*)d_in[6];
    const float* b_q  = (const float*)d_in[7];
    const float* w_k  = (const float*)d_in[8];
    const float* b_k  = (const float*)d_in[9];
    const float* w_v  = (const float*)d_in[10];
    const float* b_v  = (const float*)d_in[11];
    const float* w_a  = (const float*)d_in[12];
    const float* b_a  = (const float*)d_in[13];
    const float* w_o  = (const float*)d_in[14];
    const float* b_o  = (const float*)d_in[15];
    float* out = (float*)d_out;

    char* w = (char*)d_ws;
    int*            knnIdx = (int*)w;                                    // 1 MB
    float*          biasb  = (float*)(w + (size_t)1*(1u<<20));           // 4 MB
    float*          Qb     = (float*)(w + (size_t)5*(1u<<20));           // 32 MB
    unsigned short* Kb     = (unsigned short*)(w + (size_t)37*(1u<<20)); // 16 MB bf16
    unsigned short* Vb     = (unsigned short*)(w + (size_t)53*(1u<<20)); // 16 MB bf16
    float*          h32    = (float*)(w + (size_t)69*(1u<<20));          // 8 MB
    float4*         pk4    = (float4*)(w + (size_t)78*(1u<<20));         // 512 KB
    unsigned short* featb  = (unsigned short*)(w + (size_t)79*(1u<<20)); // 16 MB
    unsigned short* wb     = (unsigned short*)(w + (size_t)95*(1u<<20)); // 512 KB bf16 [q|k|v|o]
    unsigned short* aggb   = featb;   // featb dead after QKV GEMM; clean reuse

    // 1) fused prep: pack_pos | conv_feat | conv_w
    prep_kernel<<<4352, 256, 0, stream>>>(k3, pk4, feat, featb,
                                          w_q, w_k, w_v, w_o, wb);
    // 2) fused: QKV MFMA GEMM || kNN scan (independent; VALU/MFMA overlap)
    fused_knn_qkv<<<9728, 256, 0, stream>>>(pk4, knnIdx, featb, wb,
                                            b_q, b_k, b_v, Qb, Kb, Vb);
    // 3) geometry (needs knnIdx)
    geom_kernel<<<128, 256, 0, stream>>>(pk4, knnIdx, gw1, gb1, w_a, b_a, biasb, h32);
    // 4) fused: enc f32 GEMM || attention (independent)
    fused_enc_attn<<<8704, 256, 0, stream>>>(h32, gw2, gb2, out,
                                             Qb, Kb, Vb, knnIdx, biasb, aggb);
    // 5) out = agg @ w_o^T + b_o + enc (MFMA, no-restrict aliased epilogue)
    gemm_o_mfma<<<dim3(256, 2), 256, 0, stream>>>(aggb, wb + (size_t)3*65536, b_o, out, out);
}

// Round 24
// 175.974 us; speedup vs baseline: 1.0824x; 1.0824x over previous
//
#include <hip/hip_runtime.h>
#include <math.h>

#define NN 2048

using f32x4 = __attribute__((ext_vector_type(4))) float;
using u32x4 = __attribute__((ext_vector_type(4))) unsigned int;
using u32x2 = __attribute__((ext_vector_type(2))) unsigned int;

__device__ __forceinline__ unsigned short f2bf(float x){
    unsigned int u = __float_as_uint(x);
    return (unsigned short)((u + 0x7FFFu + ((u>>16)&1u)) >> 16);
}
__device__ __forceinline__ float bf2f(unsigned short u){
    return __uint_as_float(((unsigned int)u) << 16);
}

// v_mfma_f32_16x16x32_bf16: D(4xf32)=A(8xbf16)*B(8xbf16)+C
__device__ __forceinline__ void mfma16(f32x4& acc, const u32x4& a, const u32x4& b) {
    asm("v_mfma_f32_16x16x32_bf16 %0, %1, %2, %0" : "+v"(acc) : "v"(a), "v"(b));
}

// ---------------- 3x3 symmetric eigen (min/max) in double ----------------
__device__ inline void eig3_minmax(double a11, double a12, double a13,
                                   double a22, double a23, double a33,
                                   double& lmin, double& lmax) {
    double p1 = a12*a12 + a13*a13 + a23*a23;
    double q  = (a11 + a22 + a33) / 3.0;
    double d1 = a11 - q, d2 = a22 - q, d3 = a33 - q;
    double p2 = d1*d1 + d2*d2 + d3*d3 + 2.0*p1;
    if (p2 <= 1e-300) { lmin = q; lmax = q; return; }
    double pp  = sqrt(p2 / 6.0);
    double inv = 1.0 / pp;
    double b11 = d1*inv, b22 = d2*inv, b33 = d3*inv;
    double b12 = a12*inv, b13 = a13*inv, b23 = a23*inv;
    double detB = b11*(b22*b33 - b23*b23) - b12*(b12*b33 - b23*b13) + b13*(b12*b23 - b22*b13);
    double r = detB * 0.5;
    r = fmin(1.0, fmax(-1.0, r));
    double phi = acos(r) / 3.0;
    lmax = q + 2.0*pp*cos(phi);
    lmin = q + 2.0*pp*cos(phi + 2.0943951023931953);
}

// ---------------- fused prep: pack_pos | conv_feat | conv_w --------------
// All branches are tiny copy kernels (~16 VGPR, no LDS/scratch) -> no
// resource coupling (the R23 regression mechanism doesn't apply).
__global__ __launch_bounds__(256) void prep_kernel(
    const float* __restrict__ k3, float4* __restrict__ pk,
    const float* __restrict__ feat, unsigned short* __restrict__ featb,
    const float* __restrict__ w_q, const float* __restrict__ w_k,
    const float* __restrict__ w_v, const float* __restrict__ w_o,
    unsigned short* __restrict__ wb)
{
    const int B = blockIdx.x;
    if (B < 128) {
        const int i = B * 256 + threadIdx.x;
        const float x = k3[i*3+0], y = k3[i*3+1], z = k3[i*3+2];
        pk[i] = make_float4(x, y, z, x*x + y*y + z*z);
    } else if (B < 4224) {
        const size_t i = (size_t)((B - 128) * 256 + threadIdx.x) * 8;
        const float4 a = *(const float4*)(feat + i);
        const float4 b = *(const float4*)(feat + i + 4);
        u32x4 v;
        v.x = (unsigned)f2bf(a.x) | ((unsigned)f2bf(a.y) << 16);
        v.y = (unsigned)f2bf(a.z) | ((unsigned)f2bf(a.w) << 16);
        v.z = (unsigned)f2bf(b.x) | ((unsigned)f2bf(b.y) << 16);
        v.w = (unsigned)f2bf(b.z) | ((unsigned)f2bf(b.w) << 16);
        *(u32x4*)(featb + i) = v;
    } else {
        const int i = (B - 4224) * 256 + threadIdx.x;   // 0..32767
        const int sel = i >> 13;
        const size_t off = (size_t)(i & 8191) * 8;
        const float* src = (sel == 0) ? w_q : (sel == 1) ? w_k : (sel == 2) ? w_v : w_o;
        const float4 a = *(const float4*)(src + off);
        const float4 b = *(const float4*)(src + off + 4);
        u32x4 v;
        v.x = (unsigned)f2bf(a.x) | ((unsigned)f2bf(a.y) << 16);
        v.y = (unsigned)f2bf(a.z) | ((unsigned)f2bf(a.w) << 16);
        v.z = (unsigned)f2bf(b.x) | ((unsigned)f2bf(b.y) << 16);
        v.w = (unsigned)f2bf(b.z) | ((unsigned)f2bf(b.w) << 16);
        *(u32x4*)(wb + (size_t)sel * 65536 + off) = v;
    }
}

// ---------------- kNN scan (R19/R22-proven): values-only top-8 -----------
__global__ __launch_bounds__(256) void knn_kernel(const float4* __restrict__ pk4,
                                                  int* __restrict__ idxOut) {
    __shared__ unsigned long long hitbuf[4][16];
    __shared__ int hitcnt[4];
    const int wave = threadIdx.x >> 6, lane = threadIdx.x & 63;
    const int p = blockIdx.x * 4 + wave;
    const int b = p >> 11, n = p & (NN - 1);
    const float4* pb = pk4 + (size_t)b * NN;
    const float4 me = pb[n];
    const float xn2 = -2.f*me.x, yn2 = -2.f*me.y, zn2 = -2.f*me.z, cn = me.w;

    if (lane == 0) hitcnt[wave] = 0;

    float dk[8];
    #pragma unroll
    for (int t = 0; t < 8; ++t) dk[t] = 1e30f;
    float d2s[32];

    #define INS(c4, jj, s) { \
        float d2 = cn + c4.w; \
        d2 = fmaf(xn2, c4.x, d2); \
        d2 = fmaf(yn2, c4.y, d2); \
        d2 = fmaf(zn2, c4.z, d2); \
        if ((jj) == n) d2 = 1e30f; \
        d2s[s] = d2; \
        dk[7] = __builtin_amdgcn_fmed3f(dk[6], dk[7], d2); \
        dk[6] = __builtin_amdgcn_fmed3f(dk[5], dk[6], d2); \
        dk[5] = __builtin_amdgcn_fmed3f(dk[4], dk[5], d2); \
        dk[4] = __builtin_amdgcn_fmed3f(dk[3], dk[4], d2); \
        dk[3] = __builtin_amdgcn_fmed3f(dk[2], dk[3], d2); \
        dk[2] = __builtin_amdgcn_fmed3f(dk[1], dk[2], d2); \
        dk[1] = __builtin_amdgcn_fmed3f(dk[0], dk[1], d2); \
        dk[0] = fminf(dk[0], d2); }

    #pragma unroll
    for (int i = 0; i < 8; ++i) {
        const int j0 = lane + i * 256;
        const float4 q0 = pb[j0];
        const float4 q1 = pb[j0 + 64];
        const float4 q2 = pb[j0 + 128];
        const float4 q3 = pb[j0 + 192];
        INS(q0, j0,       i*4 + 0)
        INS(q1, j0 + 64,  i*4 + 1)
        INS(q2, j0 + 128, i*4 + 2)
        INS(q3, j0 + 192, i*4 + 3)
    }
    #undef INS

    #define CSWAPV(a,c) { float lo = fminf(dk[a], dk[c]); float hi = fmaxf(dk[a], dk[c]); dk[a] = lo; dk[c] = hi; }
    #pragma unroll
    for (int m = 1; m < 64; m <<= 1) {
        float od[8];
        #pragma unroll
        for (int t = 0; t < 8; ++t) od[t] = __shfl_xor(dk[7 - t], m);
        #pragma unroll
        for (int t = 0; t < 8; ++t) dk[t] = fminf(dk[t], od[t]);
        CSWAPV(0,4) CSWAPV(1,5) CSWAPV(2,6) CSWAPV(3,7)
        CSWAPV(0,2) CSWAPV(1,3) CSWAPV(4,6) CSWAPV(5,7)
        CSWAPV(0,1) CSWAPV(2,3) CSWAPV(4,5) CSWAPV(6,7)
    }
    #undef CSWAPV

    const float tau = dk[7];

    #pragma unroll
    for (int s = 0; s < 32; ++s) {
        if (d2s[s] <= tau) {
            const int j = lane + (s >> 2) * 256 + (s & 3) * 64;
            unsigned u = __float_as_uint(d2s[s]);
            u ^= (u >> 31) ? 0xFFFFFFFFu : 0x80000000u;
            const int slot = atomicAdd(&hitcnt[wave], 1);
            if (slot < 16)
                hitbuf[wave][slot] = ((unsigned long long)u << 32) | (unsigned)j;
        }
    }

    if (lane == 0) {
        int cnt = hitcnt[wave]; if (cnt > 16) cnt = 16;
        int outv[8];
        if (cnt == 8) {
            #pragma unroll
            for (int t = 0; t < 8; ++t)
                outv[t] = (int)(unsigned)hitbuf[wave][t];
        } else {
            unsigned used = 0;
            #pragma unroll
            for (int t = 0; t < 8; ++t) {
                unsigned long long best = ~0ull; int bi = 0;
                #pragma unroll
                for (int i = 0; i < 16; ++i) {
                    unsigned long long v = (i < cnt && !((used >> i) & 1u))
                                         ? hitbuf[wave][i] : ~0ull;
                    if (v < best) { best = v; bi = i; }
                }
                used |= 1u << bi;
                outv[t] = (int)(unsigned)best;
            }
        }
        u32x4 v0; v0.x = outv[0]; v0.y = outv[1]; v0.z = outv[2]; v0.w = outv[3];
        u32x4 v1; v1.x = outv[4]; v1.y = outv[5]; v1.z = outv[6]; v1.w = outv[7];
        *(u32x4*)(idxOut + (size_t)p * 8)     = v0;
        *(u32x4*)(idxOut + (size_t)p * 8 + 4) = v1;
    }
}

// ---------------- geometry: one LANE per point; bias f32 + h f32 ---------
__global__ __launch_bounds__(256) void geom_kernel(
    const float4* __restrict__ pk4, const int* __restrict__ knnIdx,
    const float* __restrict__ gw1, const float* __restrict__ gb1,
    const float* __restrict__ w_a, const float* __restrict__ b_a,
    float* __restrict__ biasOut, float* __restrict__ h32) {
    const int p = blockIdx.x * 256 + threadIdx.x;
    const int b = p >> 11, n = p & (NN - 1);
    const float4* pb = pk4 + (size_t)b * NN;
    const float4 me = pb[n];
    const float xn2 = -2.f*me.x, yn2 = -2.f*me.y, zn2 = -2.f*me.z, cn = me.w;

    int ik[8];
    *(u32x4*)&ik[0] = *(const u32x4*)(knnIdx + (size_t)p * 8);
    *(u32x4*)&ik[4] = *(const u32x4*)(knnIdx + (size_t)p * 8 + 4);

    float dist[8], px[8], py[8], pz[8];
    #pragma unroll
    for (int t = 0; t < 8; ++t) {
        const float4 q = pb[ik[t]];
        float d2 = cn + q.w;
        d2 = fmaf(xn2, q.x, d2);
        d2 = fmaf(yn2, q.y, d2);
        d2 = fmaf(zn2, q.z, d2);
        dist[t] = sqrtf(fmaxf(d2, 0.0f));
        px[t] = q.x; py[t] = q.y; pz[t] = q.z;
    }
    float mean = 0.f;
    #pragma unroll
    for (int t = 0; t < 8; ++t) mean += dist[t];
    mean *= 0.125f;
    float var = 0.f;
    #pragma unroll
    for (int t = 0; t < 8; ++t) { float d = dist[t] - mean; var += d * d; }
    const float stdd = sqrtf(var / 7.0f);

    float cx = 0.f, cy = 0.f, cz = 0.f;
    #pragma unroll
    for (int t = 0; t < 8; ++t) { cx += px[t]; cy += py[t]; cz += pz[t]; }
    cx *= 0.125f; cy *= 0.125f; cz *= 0.125f;
    const float relx = me.x - cx, rely = me.y - cy, relz = me.z - cz;

    double a11=0, a12=0, a13=0, a22=0, a23=0, a33=0;
    #pragma unroll
    for (int t = 0; t < 8; ++t) {
        double ux = (double)(px[t] - cx), uy = (double)(py[t] - cy), uz = (double)(pz[t] - cz);
        a11 += ux*ux; a12 += ux*uy; a13 += ux*uz;
        a22 += uy*uy; a23 += uy*uz; a33 += uz*uz;
    }
    a11 *= 0.125; a12 *= 0.125; a13 *= 0.125; a22 *= 0.125; a23 *= 0.125; a33 *= 0.125;
    double lmin, lmax;
    eig3_minmax(a11, a12, a13, a22, a23, a33, lmin, lmax);
    const float aniso = (float)(lmax / (lmin + 1e-8));

    float wa[28], ba[4];
    #pragma unroll
    for (int i = 0; i < 28; ++i) wa[i] = w_a[i];
    #pragma unroll
    for (int h = 0; h < 4; ++h) ba[h] = b_a[h];
    #pragma unroll
    for (int t = 0; t < 8; ++t) {
        f32x4 v;
        #pragma unroll
        for (int h = 0; h < 4; ++h) {
            v[h] = wa[h*7+0]*dist[t] + wa[h*7+1]*mean + wa[h*7+2]*stdd
                 + wa[h*7+3]*relx + wa[h*7+4]*rely + wa[h*7+5]*relz
                 + wa[h*7+6]*aniso + ba[h];
        }
        *(f32x4*)(biasOut + ((size_t)p*8 + t) * 4) = v;
    }

    const float g0 = mean, g1 = mean, g2 = stdd, g3 = relx, g4 = rely, g5 = relz, g6 = aniso;
    float* hrow = h32 + (size_t)p * 64;
    #pragma unroll
    for (int cq = 0; cq < 16; ++cq) {
        f32x4 hv;
        #pragma unroll
        for (int r = 0; r < 4; ++r) {
            const int c = cq*4 + r;
            float h = gw1[c*7+0]*g0 + gw1[c*7+1]*g1 + gw1[c*7+2]*g2 + gw1[c*7+3]*g3
                    + gw1[c*7+4]*g4 + gw1[c*7+5]*g5 + gw1[c*7+6]*g6 + gb1[c];
            hv[r] = fmaxf(h, 0.0f);
        }
        *(f32x4*)(hrow + cq*4) = hv;
    }
}

// ---------------- MFMA QKV GEMM (R22-proven): Q f32, K/V bf16 ------------
__global__ __launch_bounds__(256) void gemm_qkv_mfma(
    const unsigned short* __restrict__ Ab, const unsigned short* __restrict__ Wball,
    const float* __restrict__ b_q, const float* __restrict__ b_k, const float* __restrict__ b_v,
    float* __restrict__ Qb, unsigned short* __restrict__ Kb, unsigned short* __restrict__ Vb)
{
    __shared__ unsigned short As[128 * 72];
    __shared__ unsigned short Bs[128 * 72];
    const int tid = threadIdx.x;
    const int m0 = blockIdx.x * 128;
    const int wsel = blockIdx.y >> 1;
    const int crel0 = (blockIdx.y & 1) * 128;
    const unsigned short* Wb = Wball + (size_t)wsel * 65536;
    const float* bv = (wsel == 0) ? b_q : ((wsel == 1) ? b_k : b_v);

    const int sr = tid >> 1, sh = (tid & 1) * 32;
    const int wid = tid >> 6, lane = tid & 63;
    const int wr = (wid >> 1) * 64, wc = (wid & 1) * 64;
    const int l15 = lane & 15, lk = (lane >> 4) * 8, lq = (lane >> 4) * 4;

    f32x4 acc[4][4];
    #pragma unroll
    for (int i = 0; i < 4; ++i)
        #pragma unroll
        for (int j = 0; j < 4; ++j) { f32x4 z = {0.f,0.f,0.f,0.f}; acc[i][j] = z; }

    for (int k0 = 0; k0 < 256; k0 += 64) {
        const unsigned short* ga = Ab + (size_t)(m0 + sr) * 256 + k0 + sh;
        u32x4 a0 = *(const u32x4*)(ga);
        u32x4 a1 = *(const u32x4*)(ga + 8);
        u32x4 a2 = *(const u32x4*)(ga + 16);
        u32x4 a3 = *(const u32x4*)(ga + 24);
        const unsigned short* gw = Wb + (size_t)(crel0 + sr) * 256 + k0 + sh;
        u32x4 b0 = *(const u32x4*)(gw);
        u32x4 b1 = *(const u32x4*)(gw + 8);
        u32x4 b2 = *(const u32x4*)(gw + 16);
        u32x4 b3 = *(const u32x4*)(gw + 24);
        __syncthreads();
        *(u32x4*)&As[sr*72 + sh     ] = a0;
        *(u32x4*)&As[sr*72 + sh +  8] = a1;
        *(u32x4*)&As[sr*72 + sh + 16] = a2;
        *(u32x4*)&As[sr*72 + sh + 24] = a3;
        *(u32x4*)&Bs[sr*72 + sh     ] = b0;
        *(u32x4*)&Bs[sr*72 + sh +  8] = b1;
        *(u32x4*)&Bs[sr*72 + sh + 16] = b2;
        *(u32x4*)&Bs[sr*72 + sh + 24] = b3;
        __syncthreads();
        #pragma unroll
        for (int ks = 0; ks < 64; ks += 32) {
            u32x4 af[4], bfr[4];
            #pragma unroll
            for (int i = 0; i < 4; ++i)  af[i]  = *(const u32x4*)&As[(wr + i*16 + l15)*72 + ks + lk];
            #pragma unroll
            for (int j = 0; j < 4; ++j)  bfr[j] = *(const u32x4*)&Bs[(wc + j*16 + l15)*72 + ks + lk];
            #pragma unroll
            for (int i = 0; i < 4; ++i)
                #pragma unroll
                for (int j = 0; j < 4; ++j) mfma16(acc[i][j], af[i], bfr[j]);
        }
    }
    #pragma unroll
    for (int j = 0; j < 4; ++j) {
        const int col = crel0 + wc + j*16 + l15;
        const float biasv = bv[col];
        #pragma unroll
        for (int i = 0; i < 4; ++i)
            #pragma unroll
            for (int r = 0; r < 4; ++r) {
                const int m = m0 + wr + i*16 + lq + r;
                const float v = acc[i][j][r] + biasv;
                if (wsel == 0)      Qb[(size_t)m * 256 + col] = v;
                else if (wsel == 1) Kb[(size_t)m * 256 + col] = f2bf(v);
                else                Vb[(size_t)m * 256 + col] = f2bf(v);
            }
    }
}

// ---------------- MFMA O GEMM: bf16 weights; no-restrict aliased epilogue -
__global__ __launch_bounds__(256) void gemm_o_mfma(
    const unsigned short* __restrict__ Ab, const unsigned short* __restrict__ Wb,
    const float* __restrict__ bvec, const float* addin, float* C)
{
    __shared__ unsigned short As[128 * 72];
    __shared__ unsigned short Bs[128 * 72];
    const int tid = threadIdx.x;
    const int m0 = blockIdx.x * 128;
    const int crel0 = blockIdx.y * 128;

    const int sr = tid >> 1, sh = (tid & 1) * 32;
    const int wid = tid >> 6, lane = tid & 63;
    const int wr = (wid >> 1) * 64, wc = (wid & 1) * 64;
    const int l15 = lane & 15, lk = (lane >> 4) * 8, lq = (lane >> 4) * 4;

    f32x4 acc[4][4];
    #pragma unroll
    for (int i = 0; i < 4; ++i)
        #pragma unroll
        for (int j = 0; j < 4; ++j) { f32x4 z = {0.f,0.f,0.f,0.f}; acc[i][j] = z; }

    for (int k0 = 0; k0 < 256; k0 += 64) {
        const unsigned short* ga = Ab + (size_t)(m0 + sr) * 256 + k0 + sh;
        u32x4 a0 = *(const u32x4*)(ga);
        u32x4 a1 = *(const u32x4*)(ga + 8);
        u32x4 a2 = *(const u32x4*)(ga + 16);
        u32x4 a3 = *(const u32x4*)(ga + 24);
        const unsigned short* gw = Wb + (size_t)(crel0 + sr) * 256 + k0 + sh;
        u32x4 b0 = *(const u32x4*)(gw);
        u32x4 b1 = *(const u32x4*)(gw + 8);
        u32x4 b2 = *(const u32x4*)(gw + 16);
        u32x4 b3 = *(const u32x4*)(gw + 24);
        __syncthreads();
        *(u32x4*)&As[sr*72 + sh     ] = a0;
        *(u32x4*)&As[sr*72 + sh +  8] = a1;
        *(u32x4*)&As[sr*72 + sh + 16] = a2;
        *(u32x4*)&As[sr*72 + sh + 24] = a3;
        *(u32x4*)&Bs[sr*72 + sh     ] = b0;
        *(u32x4*)&Bs[sr*72 + sh +  8] = b1;
        *(u32x4*)&Bs[sr*72 + sh + 16] = b2;
        *(u32x4*)&Bs[sr*72 + sh + 24] = b3;
        __syncthreads();
        #pragma unroll
        for (int ks = 0; ks < 64; ks += 32) {
            u32x4 af[4], bfr[4];
            #pragma unroll
            for (int i = 0; i < 4; ++i)  af[i]  = *(const u32x4*)&As[(wr + i*16 + l15)*72 + ks + lk];
            #pragma unroll
            for (int j = 0; j < 4; ++j)  bfr[j] = *(const u32x4*)&Bs[(wc + j*16 + l15)*72 + ks + lk];
            #pragma unroll
            for (int i = 0; i < 4; ++i)
                #pragma unroll
                for (int j = 0; j < 4; ++j) mfma16(acc[i][j], af[i], bfr[j]);
        }
    }
    #pragma unroll
    for (int j = 0; j < 4; ++j) {
        const int col = crel0 + wc + j*16 + l15;
        const float biasv = bvec[col];
        #pragma unroll
        for (int i = 0; i < 4; ++i)
            #pragma unroll
            for (int r = 0; r < 4; ++r) {
                const int m = m0 + wr + i*16 + lq + r;
                const float ad = addin[(size_t)m * 256 + col];
                C[(size_t)m * 256 + col] = acc[i][j][r] + biasv + ad;
            }
    }
}

// ---------------- f32 GEMM 128x128 (enc only, K=64) ----------------------
template<int K>
__global__ __launch_bounds__(256) void gemm_f32_big(
    const float* __restrict__ A, const float* __restrict__ W,
    const float* __restrict__ bvec, float* __restrict__ C)
{
    __shared__ float As[16][132];
    __shared__ float Bs[16][132];
    const int tid = threadIdx.x;
    const int m0 = blockIdx.x * 128;
    const int c0 = blockIdx.y * 128;
    const int tx = tid & 15;
    const int ty = tid >> 4;
    const int lr = tid & 127;
    const int kh = (tid >> 7) * 8;

    float acc[8][8] = {};

    const float* ga = A + (size_t)(m0 + lr) * K + kh;
    const float* gb = W + (size_t)(c0 + lr) * K + kh;

    float4 av0 = *(const float4*)(ga);
    float4 av1 = *(const float4*)(ga + 4);
    float4 bv0 = *(const float4*)(gb);
    float4 bv1 = *(const float4*)(gb + 4);

    for (int k0 = 0; k0 < K; k0 += 16) {
        __syncthreads();
        As[kh+0][lr]=av0.x; As[kh+1][lr]=av0.y; As[kh+2][lr]=av0.z; As[kh+3][lr]=av0.w;
        As[kh+4][lr]=av1.x; As[kh+5][lr]=av1.y; As[kh+6][lr]=av1.z; As[kh+7][lr]=av1.w;
        Bs[kh+0][lr]=bv0.x; Bs[kh+1][lr]=bv0.y; Bs[kh+2][lr]=bv0.z; Bs[kh+3][lr]=bv0.w;
        Bs[kh+4][lr]=bv1.x; Bs[kh+5][lr]=bv1.y; Bs[kh+6][lr]=bv1.z; Bs[kh+7][lr]=bv1.w;
        if (k0 + 16 < K) {
            av0 = *(const float4*)(ga + k0 + 16);
            av1 = *(const float4*)(ga + k0 + 20);
            bv0 = *(const float4*)(gb + k0 + 16);
            bv1 = *(const float4*)(gb + k0 + 20);
        }
        __syncthreads();
        #pragma unroll
        for (int kk = 0; kk < 16; ++kk) {
            const float4 a0 = *(const float4*)&As[kk][ty*8];
            const float4 a1 = *(const float4*)&As[kk][ty*8+4];
            const float4 b0 = *(const float4*)&Bs[kk][tx*8];
            const float4 b1 = *(const float4*)&Bs[kk][tx*8+4];
            const float a[8] = {a0.x,a0.y,a0.z,a0.w,a1.x,a1.y,a1.z,a1.w};
            const float b[8] = {b0.x,b0.y,b0.z,b0.w,b1.x,b1.y,b1.z,b1.w};
            #pragma unroll
            for (int i = 0; i < 8; ++i)
                #pragma unroll
                for (int j = 0; j < 8; ++j)
                    acc[i][j] = fmaf(a[i], b[j], acc[i][j]);
        }
    }
    #pragma unroll
    for (int i = 0; i < 8; ++i) {
        const size_t m = m0 + ty*8 + i;
        const int c = c0 + tx*8;
        float4 v0, v1;
        v0.x = acc[i][0] + bvec[c+0];
        v0.y = acc[i][1] + bvec[c+1];
        v0.z = acc[i][2] + bvec[c+2];
        v0.w = acc[i][3] + bvec[c+3];
        v1.x = acc[i][4] + bvec[c+4];
        v1.y = acc[i][5] + bvec[c+5];
        v1.z = acc[i][6] + bvec[c+6];
        v1.w = acc[i][7] + bvec[c+7];
        *(float4*)(C + m*256 + c)     = v0;
        *(float4*)(C + m*256 + c + 4) = v1;
    }
}

// ---------------- gather attention: batch->XCD swizzle; agg -> bf16 ------
__global__ __launch_bounds__(256) void attn_kernel(
    const float* __restrict__ Qb, const unsigned short* __restrict__ Kb,
    const unsigned short* __restrict__ Vb, const int* __restrict__ knnIdx,
    const float* __restrict__ biasb, unsigned short* __restrict__ aggb)
{
    const int wave = threadIdx.x >> 6;
    const int lane = threadIdx.x & 63;
    const int B = blockIdx.x;
    const int xcd = B & 7;
    const int k = B >> 3;                       // 0..1023
    const int batch = xcd + ((k >= 512) ? 8 : 0);
    const int p = batch * NN + ((k & 511) << 2) + wave;
    const int b = batch;
    const int h = lane >> 4;

    const float4 q = *(const float4*)(Qb + (size_t)p*256 + lane*4);

    int g[8];
    #pragma unroll
    for (int t = 0; t < 8; ++t) g[t] = b * NN + knnIdx[(size_t)p*8 + t];

    float s[8];
    #pragma unroll
    for (int t = 0; t < 8; ++t) {
        const ushort4 kv = *(const ushort4*)(Kb + (size_t)g[t]*256 + lane*4);
        float acc = q.x * bf2f(kv.x);
        acc = fmaf(q.y, bf2f(kv.y), acc);
        acc = fmaf(q.z, bf2f(kv.z), acc);
        acc = fmaf(q.w, bf2f(kv.w), acc);
        acc += __shfl_xor(acc, 1);
        acc += __shfl_xor(acc, 2);
        acc += __shfl_xor(acc, 4);
        acc += __shfl_xor(acc, 8);
        s[t] = acc * 0.125f + biasb[((size_t)p*8 + t)*4 + h];
    }

    float mx = s[0];
    #pragma unroll
    for (int t = 1; t < 8; ++t) mx = fmaxf(mx, s[t]);
    float sum = 0.f;
    #pragma unroll
    for (int t = 0; t < 8; ++t) { s[t] = expf(s[t] - mx); sum += s[t]; }
    const float inv = 1.0f / sum;

    f32x4 a = {0.f, 0.f, 0.f, 0.f};
    #pragma unroll
    for (int t = 0; t < 8; ++t) {
        const float wgt = s[t] * inv;
        const ushort4 vv = *(const ushort4*)(Vb + (size_t)g[t]*256 + lane*4);
        a[0] = fmaf(wgt, bf2f(vv.x), a[0]);
        a[1] = fmaf(wgt, bf2f(vv.y), a[1]);
        a[2] = fmaf(wgt, bf2f(vv.z), a[2]);
        a[3] = fmaf(wgt, bf2f(vv.w), a[3]);
    }
    u32x2 pk;
    pk.x = (unsigned)f2bf(a[0]) | ((unsigned)f2bf(a[1]) << 16);
    pk.y = (unsigned)f2bf(a[2]) | ((unsigned)f2bf(a[3]) << 16);
    *(u32x2*)(aggb + (size_t)p*256 + lane*4) = pk;
}

extern "C" void kernel_launch(void* const* d_in, const int* in_sizes, int n_in,
                              void* d_out, int out_size, void* d_ws, size_t ws_size,
                              hipStream_t stream) {
    const float* feat = (const float*)d_in[0];
    const float* k3   = (const float*)d_in[1];
    const float* gw1  = (const float*)d_in[2];
    const float* gb1  = (const float*)d_in[3];
    const float* gw2  = (const float*)d_in[4];
    const float* gb2  = (const float*)d_in[5];
    const float* w_q  = (const float*)d_in[6];
    const float* b_q  = (const float*)d_in[7];
    const float* w_k  = (const float*)d_in[8];
    const float* b_k  = (const float*)d_in[9];
    const float* w_v  = (const float*)d_in[10];
    const float* b_v  = (const float*)d_in[11];
    const float* w_a  = (const float*)d_in[12];
    const float* b_a  = (const float*)d_in[13];
    const float* w_o  = (const float*)d_in[14];
    const float* b_o  = (const float*)d_in[15];
    float* out = (float*)d_out;

    char* w = (char*)d_ws;
    int*            knnIdx = (int*)w;                                    // 1 MB
    float*          biasb  = (float*)(w + (size_t)1*(1u<<20));           // 4 MB
    float*          Qb     = (float*)(w + (size_t)5*(1u<<20));           // 32 MB
    unsigned short* Kb     = (unsigned short*)(w + (size_t)37*(1u<<20)); // 16 MB bf16
    unsigned short* Vb     = (unsigned short*)(w + (size_t)53*(1u<<20)); // 16 MB bf16
    float*          h32    = (float*)(w + (size_t)69*(1u<<20));          // 8 MB
    float4*         pk4    = (float4*)(w + (size_t)78*(1u<<20));         // 512 KB
    unsigned short* featb  = (unsigned short*)(w + (size_t)79*(1u<<20)); // 16 MB
    unsigned short* wb     = (unsigned short*)(w + (size_t)95*(1u<<20)); // 512 KB bf16 [q|k|v|o]
    unsigned short* aggb   = featb;   // featb dead after QKV GEMM; clean reuse

    // 1) fused prep: pack_pos | conv_feat | conv_w (tiny, no resource coupling)
    prep_kernel<<<4352, 256, 0, stream>>>(k3, pk4, feat, featb,
                                          w_q, w_k, w_v, w_o, wb);
    // 2) kNN scan (R19/R22-proven standalone form)
    knn_kernel<<<8192, 256, 0, stream>>>(pk4, knnIdx);
    // 3) geometry
    geom_kernel<<<128, 256, 0, stream>>>(pk4, knnIdx, gw1, gb1, w_a, b_a, biasb, h32);
    // 4) enc (f32): out = h32 @ gw2^T + gb2
    gemm_f32_big<64><<<dim3(256, 2), 256, 0, stream>>>(h32, gw2, gb2, out);
    // 5) Q/K/V via MFMA with pre-converted bf16 weights
    gemm_qkv_mfma<<<dim3(256, 6), 256, 0, stream>>>(featb, wb, b_q, b_k, b_v, Qb, Kb, Vb);
    // 6) gather attention (batch->XCD swizzled); bf16 agg into featb (dead)
    attn_kernel<<<8192, 256, 0, stream>>>(Qb, Kb, Vb, knnIdx, biasb, aggb);
    // 7) out = agg @ w_o^T + b_o + enc (MFMA, no-restrict aliased epilogue)
    gemm_o_mfma<<<dim3(256, 2), 256, 0, stream>>>(aggb, wb + (size_t)3*65536, b_o, out, out);
}